// Round 5
// baseline (157.767 us; speedup 1.0000x reference)
//
#include <hip/hip_runtime.h>
#include <math.h>

#define NRAY2 4096
#define NSAMP 64
#define PHD 192
#define PLANE (PHD*PHD)          // 36864
constexpr float STEP = 1.0f / 63.0f;

struct Mats { float crd[16]; float drv[16]; };

// ---------------- host-side constant matrices (replicates numpy fp64 math) ---
static void mat_mul4(const double* A, const double* B, double* C) {
    for (int i = 0; i < 4; ++i)
        for (int j = 0; j < 4; ++j) {
            double s = 0.0;
            for (int k = 0; k < 4; ++k) s += A[i*4+k] * B[k*4+j];
            C[i*4+j] = s;
        }
}

static void build_mats(Mats& M) {
    const double tx = 0.1, ty = 0.05, tz = 0.02;
    const double cx = 0.5, cy = 0.5, cz = 0.5;
    auto ry = [](double t, double* m) {
        double c = cos(t), s = sin(t);
        double v[16] = {1,0,0,0, 0,c,-s,0, 0,s,c,0, 0,0,0,1};
        for (int i = 0; i < 16; ++i) m[i] = v[i];
    };
    auto rx = [](double t, double* m) {
        double c = cos(t), s = sin(t);
        double v[16] = {c,0,-s,0, 0,1,0,0, s,0,c,0, 0,0,0,1};
        for (int i = 0; i < 16; ++i) m[i] = v[i];
    };
    auto rz = [](double t, double* m) {
        double c = cos(t), s = sin(t);
        double v[16] = {c,-s,0,0, s,c,0,0, 0,0,1,0, 0,0,0,1};
        for (int i = 0; i < 16; ++i) m[i] = v[i];
    };
    double RY[16], RY_[16], RX[16], RX_[16], RZ[16], RZ_[16];
    ry(-ty, RY); ry(ty, RY_);
    rx(tx, RX);  rx(-tx, RX_);
    rz(-tz, RZ); rz(tz, RZ_);
    double S1[16] = {1,0,0,0, 0,1,0,0, 0,0,1,0, -cx,-cy,-cz,1};
    double S2[16] = {1,0,0,0, 0,1,0,0, 0,0,1,0,  cx, cy, cz,1};
    double t1[16], t2[16], t3[16], Mc[16], Md[16];
    mat_mul4(S1, RZ, t1);
    mat_mul4(t1, RY, t2);
    mat_mul4(t2, RX, t3);
    mat_mul4(t3, S2, Mc);
    mat_mul4(RX_, RY_, t1);
    mat_mul4(t1, RZ_, Md);
    for (int i = 0; i < 16; ++i) { M.crd[i] = (float)Mc[i]; M.drv[i] = (float)Md[i]; }
}

// One butterfly level applied to all 8 values: 8 independent DPP moves then
// 8 adds -> the dependent chains of the 8 reductions overlap instead of
// serializing (the R4 bottleneck: 8 sequential red32 calls each stalled on
// its own ds_swizzle wait).
template<int CTRL>
__device__ __forceinline__ void dpp_level8(float* v) {
    int t[8];
    #pragma unroll
    for (int i = 0; i < 8; ++i)
        t[i] = __builtin_amdgcn_update_dpp(0, __float_as_int(v[i]), CTRL, 0xF, 0xF, true);
    #pragma unroll
    for (int i = 0; i < 8; ++i) v[i] += __int_as_float(t[i]);
}

// 32-lane allreduce of 8 values, level-interleaved; final xor-16 via 8
// back-to-back ds_swizzles (one lgkm wait covers all 8).
__device__ __forceinline__ void red8(float* v) {
    dpp_level8<0x121>(v);   // row_ror:1
    dpp_level8<0x122>(v);   // row_ror:2
    dpp_level8<0x124>(v);   // row_ror:4
    dpp_level8<0x128>(v);   // row_ror:8
    int t[8];
    #pragma unroll
    for (int i = 0; i < 8; ++i)
        t[i] = __builtin_amdgcn_ds_swizzle(__float_as_int(v[i]), 0x401F); // lane^16
    #pragma unroll
    for (int i = 0; i < 8; ++i) v[i] += __int_as_float(t[i]);
}

// ---------------- kernel 1: ray tracing -------------------------------------
__global__ __launch_bounds__(256) void ray_trace_kernel(
    const float* __restrict__ RI,       // (64^3, 2) interleaved [A, sig]
    const float* __restrict__ RayInit,  // (4096, 5)
    float* __restrict__ meshXT,         // (64, 4096)  stores 2X-1
    float* __restrict__ meshYT,         // (64, 4096)  stores 2Y-1
    Mats M)
{
    const int tid = threadIdx.x;
    const int nb  = tid & 31;
    const int ray = blockIdx.x * 8 + (tid >> 5);
    const bool act = nb < 27;

    float xr = 0.f, yr = 0.f, zr = 0.f;
    if (act) {
        int a0 = nb / 9, a1 = (nb / 3) % 3, a2 = nb % 3;
        xr = (float)(a1 - 1);
        yr = (float)(a0 - 1);
        zr = (float)(a2 - 1);
    }

    float X  = RayInit[ray*5 + 0];
    float dX = RayInit[ray*5 + 1];
    float Y  = RayInit[ray*5 + 2];
    float dY = RayInit[ray*5 + 3];
    float z  = RayInit[ray*5 + 4];

    if (nb == 0) meshXT[ray] = X*2.0f - 1.0f;
    if (nb == 1) meshYT[ray] = Y*2.0f - 1.0f;

    auto prep = [&](float pX, float pY, float pz,
                    float& ox, float& oy, float& oz,
                    float& oXn, float& oYn, float& oZn) -> const float2* {
        float x  = pY*M.crd[1] + pX*M.crd[5] + pz*M.crd[9]  + M.crd[13];
        float y  = pY*M.crd[0] + pX*M.crd[4] + pz*M.crd[8]  + M.crd[12];
        float zz = pY*M.crd[2] + pX*M.crd[6] + pz*M.crd[10] + M.crd[14];
        float XnL = __builtin_amdgcn_fmed3f(rintf(x *64.0f) + xr, 0.0f, 63.0f);
        float YnL = __builtin_amdgcn_fmed3f(rintf(y *64.0f) + yr, 0.0f, 63.0f);
        float ZnL = __builtin_amdgcn_fmed3f(rintf(zz*64.0f) + zr, 0.0f, 63.0f);
        int lin = (int)(YnL*4096.0f + XnL*64.0f + ZnL);   // exact in fp32
        ox = x; oy = y; oz = zz; oXn = XnL; oYn = YnL; oZn = ZnL;
        return (const float2*)RI + lin;
    };

    float cx_, cy_, cz_, Xn, Yn, Zn;
    float2 ri = *prep(X, Y, z, cx_, cy_, cz_, Xn, Yn, Zn);

    for (int s = 1; s < NSAMP; ++s) {
        // one-step-ahead RI prefetch
        float nX = X + dX*STEP, nY = Y + dY*STEP, nz = z + STEP;
        float ncx, ncy, ncz, nXn, nYn, nZn;
        float2 ri_n = *prep(nX, nY, nz, ncx, ncy, ncz, nXn, nYn, nZn);

        float dx = Xn*(1.0f/63.0f) - cx_;
        float dy = Yn*(1.0f/63.0f) - cy_;
        float dz = Zn*(1.0f/63.0f) - cz_;
        float inv_s2 = __builtin_amdgcn_rcpf(ri.y * ri.y);
        float e = __expf(-(dx*dx + dy*dy + dz*dz) * 0.5f * inv_s2) + 2e-7f;
        if (!act) e = 0.0f;
        float gdx = dx*inv_s2, gdy = dy*inv_s2, gdz = dz*inv_s2;
        float nu  = e * ri.x;

        float v[8] = { e, nu, nu*gdx, nu*gdy, nu*gdz, e*gdx, e*gdy, e*gdz };
        red8(v);
        float ni  = v[0], nuA = v[1];
        float sx  = v[2], sy  = v[3], sz  = v[4];
        float sdx = v[5], sdy = v[6], sdz = v[7];

        float r   = __builtin_amdgcn_rcpf(ni);
        float rn  = ni * __builtin_amdgcn_rcpf(nuA);   // 1/n = norm/nu_s
        float in2 = r * r;
        float gx_ = (ni*sx - nuA*sdx) * in2;
        float gy_ = (ni*sy - nuA*sdy) * in2;
        float gz_ = (ni*sz - nuA*sdz) * in2;

        float dndx = gy_*M.drv[1] + gx_*M.drv[5] + gz_*M.drv[9]  + M.drv[13];
        float dndy = gy_*M.drv[0] + gx_*M.drv[4] + gz_*M.drv[8]  + M.drv[12];
        float dndz = gy_*M.drv[2] + gx_*M.drv[6] + gz_*M.drv[10] + M.drv[14];

        float dX2 = (dndx - dndz*dX) * (1.0f + dX*dX) * rn;
        float dY2 = (dndy - dndz*dY) * (1.0f + dY*dY) * rn;

        X = nX; Y = nY; z = nz;
        dX += dX2 * STEP;
        dY += dY2 * STEP;

        if (nb == 0) meshXT[s*NRAY2 + ray] = X*2.0f - 1.0f;
        if (nb == 1) meshYT[s*NRAY2 + ray] = Y*2.0f - 1.0f;

        cx_ = ncx; cy_ = ncy; cz_ = ncz;
        Xn = nXn; Yn = nYn; Zn = nZn;
        ri = ri_n;
    }
}

// ---------------- kernel 2: fused resize + grid sample ----------------------
typedef _Float16 h16;
typedef _Float16 h16v4 __attribute__((ext_vector_type(4)));

__global__ __launch_bounds__(1024) void sample_kernel(
    const float* __restrict__ vol,      // 192^3
    const float* __restrict__ meshXT,   // (64, 4096)
    const float* __restrict__ meshYT,
    h16*   __restrict__ outTh,          // fp16 transposed out [c][a*192+b]
    float* __restrict__ outDirect,      // fallback fp32 out [a][b][c]
    int transposed)
{
    __shared__ h16    plane_h[PLANE];     // 73,728 B
    __shared__ float2 slice[64*64];       // 32,768 B
    __shared__ float  wTab[PHD];
    __shared__ int    iTab[PHD];

    const int tid = threadIdx.x;
    const int blk = blockIdx.x;
    const int c = (blk >> 3) + 24 * (blk & 7);   // consecutive c on same XCD

    if (tid < PHD) {
        float p = tid * (63.0f / 191.0f);
        int i0 = min((int)p, 62);
        iTab[tid] = i0;
        wTab[tid] = p - (float)i0;
    }

    {
        const float4* src = (const float4*)(vol + c * PLANE);
        h16v4* dst = (h16v4*)plane_h;
        #pragma unroll
        for (int k = 0; k < (PLANE/4)/1024; ++k) {
            float4 v = src[tid + k*1024];
            h16v4 hv = {(h16)v.x, (h16)v.y, (h16)v.z, (h16)v.w};
            dst[tid + k*1024] = hv;
        }
    }

    float ps = c * (63.0f / 191.0f);
    int s0 = min((int)ps, 62);
    float wc = ps - (float)s0, wc0 = 1.0f - wc;
    {
        const float* x0 = meshXT + s0*NRAY2;
        const float* x1 = meshXT + (s0+1)*NRAY2;
        const float* y0 = meshYT + s0*NRAY2;
        const float* y1 = meshYT + (s0+1)*NRAY2;
        #pragma unroll
        for (int k = 0; k < 4096/1024; ++k) {
            int t = tid + k*1024;
            slice[t] = make_float2(x0[t]*wc0 + x1[t]*wc,
                                   y0[t]*wc0 + y1[t]*wc);
        }
    }
    __syncthreads();

    int a = tid / PHD, b = tid % PHD;
    #pragma unroll 2
    for (int k = 0; k < PLANE/1024; ++k) {
        int i0 = iTab[a]; float wa = wTab[a];
        int j0 = iTab[b]; float wb = wTab[b];

        float2 s00 = slice[i0*64 + j0];
        float2 s01 = slice[i0*64 + j0 + 1];
        float2 s10 = slice[(i0+1)*64 + j0];
        float2 s11 = slice[(i0+1)*64 + j0 + 1];

        float wb0 = 1.0f - wb, wa0 = 1.0f - wa;
        float gx = (s00.x*wb0 + s01.x*wb)*wa0 + (s10.x*wb0 + s11.x*wb)*wa;
        float gy = (s00.y*wb0 + s01.y*wb)*wa0 + (s10.y*wb0 + s11.y*wb)*wa;

        float ix = (gx + 1.0f) * 0.5f * 191.0f;
        float iy = (gy + 1.0f) * 0.5f * 191.0f;
        float x0f = floorf(ix); float fx = ix - x0f;
        float y0f = floorf(iy); float fy = iy - y0f;

        float acc = 0.0f;
        #pragma unroll
        for (int dyy = 0; dyy < 2; ++dyy) {
            #pragma unroll
            for (int dxx = 0; dxx < 2; ++dxx) {
                float xi = x0f + (float)dxx;
                float yi = y0f + (float)dyy;
                bool inb = (xi >= 0.0f) && (xi <= 191.0f) &&
                           (yi >= 0.0f) && (yi <= 191.0f);
                int xc = min(max((int)xi, 0), PHD - 1);
                int yc = min(max((int)yi, 0), PHD - 1);
                float w = (dxx ? fx : 1.0f - fx) * (dyy ? fy : 1.0f - fy);
                float val = (float)plane_h[yc*PHD + xc];
                acc += inb ? w * val : 0.0f;
            }
        }

        if (transposed) {
            outTh[c*PLANE + tid + k*1024] = (h16)acc;   // contiguous
        } else {
            outDirect[(a*PHD + b)*PHD + c] = acc;
        }

        a += 5; b += 64;
        if (b >= PHD) { b -= PHD; a += 1; }
    }
}

// ---------------- kernel 3: (b,c) tile transpose, fp16 -> fp32 --------------
// out[a][b][c] = (float)outTh[c][a*192 + b]; 64x64 tiles, stride-66 padding
// makes the column reads conflict-free.
__global__ __launch_bounds__(256) void transpose_kernel(
    const h16* __restrict__ outTh, float* __restrict__ out)
{
    __shared__ h16 t[64][66];
    const int a  = blockIdx.z;
    const int b0 = blockIdx.x * 64;
    const int c0 = blockIdx.y * 64;
    const int tx = threadIdx.x & 63;
    const int ty = threadIdx.x >> 6;     // 0..3

    const h16* src = outTh + (size_t)(c0 + ty) * PLANE + a*PHD + b0 + tx;
    #pragma unroll
    for (int j = 0; j < 16; ++j)
        t[ty + 4*j][tx] = src[(size_t)(4*j) * PLANE];
    __syncthreads();

    float* dst = out + (size_t)a * PLANE + (size_t)(b0 + ty) * PHD + c0 + tx;
    #pragma unroll
    for (int j = 0; j < 16; ++j)
        dst[(size_t)(4*j) * PHD] = (float)t[tx][ty + 4*j];
}

// ---------------- launch -----------------------------------------------------
extern "C" void kernel_launch(void* const* d_in, const int* in_sizes, int n_in,
                              void* d_out, int out_size, void* d_ws, size_t ws_size,
                              hipStream_t stream)
{
    const float* Phantom = (const float*)d_in[0];   // 192^3
    const float* RI      = (const float*)d_in[1];   // (64^3, 2)
    const float* RayInit = (const float*)d_in[2];   // (4096, 5)
    float* out = (float*)d_out;

    float* meshXT = (float*)d_ws;                   // (64, 4096)   1 MB
    float* meshYT = meshXT + NRAY2 * NSAMP;         // (64, 4096)   1 MB
    h16*   outTh  = (h16*)(meshYT + NRAY2 * NSAMP); // 192^3 fp16   14.2 MB

    const size_t need = (size_t)(2 * NRAY2 * NSAMP) * sizeof(float)
                      + (size_t)PHD * PLANE * sizeof(h16);
    const int use_transpose = (ws_size >= need) ? 1 : 0;

    Mats M;
    build_mats(M);

    ray_trace_kernel<<<NRAY2/8, 256, 0, stream>>>(RI, RayInit, meshXT, meshYT, M);

    if (use_transpose) {
        sample_kernel<<<PHD, 1024, 0, stream>>>(Phantom, meshXT, meshYT,
                                                outTh, nullptr, 1);
        transpose_kernel<<<dim3(3, 3, PHD), 256, 0, stream>>>(outTh, out);
    } else {
        sample_kernel<<<PHD, 1024, 0, stream>>>(Phantom, meshXT, meshYT,
                                                nullptr, out, 0);
    }
}

// Round 6
// 151.645 us; speedup vs baseline: 1.0404x; 1.0404x over previous
//
#include <hip/hip_runtime.h>
#include <math.h>

#define NRAY2 4096
#define NSAMP 64
#define PHD 192
#define PLANE (PHD*PHD)          // 36864
constexpr float STEP = 1.0f / 63.0f;

struct Mats { float crd[16]; float drv[16]; };

// ---------------- host-side constant matrices (replicates numpy fp64 math) ---
static void mat_mul4(const double* A, const double* B, double* C) {
    for (int i = 0; i < 4; ++i)
        for (int j = 0; j < 4; ++j) {
            double s = 0.0;
            for (int k = 0; k < 4; ++k) s += A[i*4+k] * B[k*4+j];
            C[i*4+j] = s;
        }
}

static void build_mats(Mats& M) {
    const double tx = 0.1, ty = 0.05, tz = 0.02;
    const double cx = 0.5, cy = 0.5, cz = 0.5;
    auto ry = [](double t, double* m) {
        double c = cos(t), s = sin(t);
        double v[16] = {1,0,0,0, 0,c,-s,0, 0,s,c,0, 0,0,0,1};
        for (int i = 0; i < 16; ++i) m[i] = v[i];
    };
    auto rx = [](double t, double* m) {
        double c = cos(t), s = sin(t);
        double v[16] = {c,0,-s,0, 0,1,0,0, s,0,c,0, 0,0,0,1};
        for (int i = 0; i < 16; ++i) m[i] = v[i];
    };
    auto rz = [](double t, double* m) {
        double c = cos(t), s = sin(t);
        double v[16] = {c,-s,0,0, s,c,0,0, 0,0,1,0, 0,0,0,1};
        for (int i = 0; i < 16; ++i) m[i] = v[i];
    };
    double RY[16], RY_[16], RX[16], RX_[16], RZ[16], RZ_[16];
    ry(-ty, RY); ry(ty, RY_);
    rx(tx, RX);  rx(-tx, RX_);
    rz(-tz, RZ); rz(tz, RZ_);
    double S1[16] = {1,0,0,0, 0,1,0,0, 0,0,1,0, -cx,-cy,-cz,1};
    double S2[16] = {1,0,0,0, 0,1,0,0, 0,0,1,0,  cx, cy, cz,1};
    double t1[16], t2[16], t3[16], Mc[16], Md[16];
    mat_mul4(S1, RZ, t1);
    mat_mul4(t1, RY, t2);
    mat_mul4(t2, RX, t3);
    mat_mul4(t3, S2, Mc);
    mat_mul4(RX_, RY_, t1);
    mat_mul4(t1, RZ_, Md);
    for (int i = 0; i < 16; ++i) { M.crd[i] = (float)Mc[i]; M.drv[i] = (float)Md[i]; }
}

// One butterfly level applied to all 8 values (chains overlap).
template<int CTRL>
__device__ __forceinline__ void dpp_level8(float* v) {
    int t[8];
    #pragma unroll
    for (int i = 0; i < 8; ++i)
        t[i] = __builtin_amdgcn_update_dpp(0, __float_as_int(v[i]), CTRL, 0xF, 0xF, true);
    #pragma unroll
    for (int i = 0; i < 8; ++i) v[i] += __int_as_float(t[i]);
}

// 16-lane allreduce of 8 values: 4 pure-DPP row_ror levels (1,2,4,8) within a
// 16-row. NO ds_swizzle, NO LDS wait — the R5 chain's lgkm stall is gone.
__device__ __forceinline__ void red8_16(float* v) {
    dpp_level8<0x121>(v);   // row_ror:1
    dpp_level8<0x122>(v);   // row_ror:2
    dpp_level8<0x124>(v);   // row_ror:4
    dpp_level8<0x128>(v);   // row_ror:8
}

// ---------------- kernel 1: ray tracing -------------------------------------
// 16 lanes per ray, 2 neighbors per lane (lane nb handles neighbors nb and
// nb+16; nb+16 inactive for nb>=11). 4 rays/wave, 1024 waves total.
__global__ __launch_bounds__(256) void ray_trace_kernel(
    const float* __restrict__ RI,       // (64^3, 2) interleaved [A, sig]
    const float* __restrict__ RayInit,  // (4096, 5)
    float* __restrict__ meshXT,         // (64, 4096)  stores 2X-1
    float* __restrict__ meshYT,         // (64, 4096)  stores 2Y-1
    Mats M)
{
    const int tid = threadIdx.x;
    const int nb  = tid & 15;                        // lane within 16-row
    const int ray = blockIdx.x * 16 + (tid >> 4);
    const bool act2 = nb < 11;                       // second neighbor active

    const int n1 = nb, n2 = nb + 16;
    const float xr1 = (float)((n1/3)%3 - 1), yr1 = (float)(n1/9 - 1), zr1 = (float)(n1%3 - 1);
    const float xr2 = (float)((n2/3)%3 - 1), yr2 = (float)(n2/9 - 1), zr2 = (float)(n2%3 - 1);

    float X  = RayInit[ray*5 + 0];
    float dX = RayInit[ray*5 + 1];
    float Y  = RayInit[ray*5 + 2];
    float dY = RayInit[ray*5 + 3];
    float z  = RayInit[ray*5 + 4];

    if (nb == 0) meshXT[ray] = X*2.0f - 1.0f;
    if (nb == 1) meshYT[ray] = Y*2.0f - 1.0f;

    // transform + both neighbor cells + issue both gathers
    auto prep = [&](float pX, float pY, float pz,
                    float& ox, float& oy, float& oz,
                    float& X1, float& Y1, float& Z1,
                    float& X2, float& Y2, float& Z2,
                    float2& r1, float2& r2) {
        float x  = pY*M.crd[1] + pX*M.crd[5] + pz*M.crd[9]  + M.crd[13];
        float y  = pY*M.crd[0] + pX*M.crd[4] + pz*M.crd[8]  + M.crd[12];
        float zz = pY*M.crd[2] + pX*M.crd[6] + pz*M.crd[10] + M.crd[14];
        float rx_ = rintf(x*64.0f), ry_ = rintf(y*64.0f), rz_ = rintf(zz*64.0f);
        X1 = __builtin_amdgcn_fmed3f(rx_ + xr1, 0.0f, 63.0f);
        Y1 = __builtin_amdgcn_fmed3f(ry_ + yr1, 0.0f, 63.0f);
        Z1 = __builtin_amdgcn_fmed3f(rz_ + zr1, 0.0f, 63.0f);
        X2 = __builtin_amdgcn_fmed3f(rx_ + xr2, 0.0f, 63.0f);
        Y2 = __builtin_amdgcn_fmed3f(ry_ + yr2, 0.0f, 63.0f);
        Z2 = __builtin_amdgcn_fmed3f(rz_ + zr2, 0.0f, 63.0f);
        int l1 = (int)(Y1*4096.0f + X1*64.0f + Z1);   // exact in fp32
        int l2 = (int)(Y2*4096.0f + X2*64.0f + Z2);
        r1 = ((const float2*)RI)[l1];
        r2 = ((const float2*)RI)[l2];
        ox = x; oy = y; oz = zz;
    };

    float cx_, cy_, cz_, Xn1, Yn1, Zn1, Xn2, Yn2, Zn2;
    float2 ri1, ri2;
    prep(X, Y, z, cx_, cy_, cz_, Xn1, Yn1, Zn1, Xn2, Yn2, Zn2, ri1, ri2);

    for (int s = 1; s < NSAMP; ++s) {
        // one-step-ahead prefetch (uses only pre-reduction state)
        float nX = X + dX*STEP, nY = Y + dY*STEP, nz = z + STEP;
        float ncx, ncy, ncz, mX1, mY1, mZ1, mX2, mY2, mZ2;
        float2 ri1n, ri2n;
        prep(nX, nY, nz, ncx, ncy, ncz, mX1, mY1, mZ1, mX2, mY2, mZ2, ri1n, ri2n);

        // neighbor 1 contribution
        float dx1 = Xn1*(1.0f/63.0f) - cx_;
        float dy1 = Yn1*(1.0f/63.0f) - cy_;
        float dz1 = Zn1*(1.0f/63.0f) - cz_;
        float is1 = __builtin_amdgcn_rcpf(ri1.y * ri1.y);
        float e1  = __expf(-(dx1*dx1 + dy1*dy1 + dz1*dz1) * 0.5f * is1) + 2e-7f;
        float g1x = dx1*is1, g1y = dy1*is1, g1z = dz1*is1;
        float nu1 = e1 * ri1.x;

        // neighbor 2 contribution (zeroed when inactive)
        float dx2 = Xn2*(1.0f/63.0f) - cx_;
        float dy2 = Yn2*(1.0f/63.0f) - cy_;
        float dz2 = Zn2*(1.0f/63.0f) - cz_;
        float is2 = __builtin_amdgcn_rcpf(ri2.y * ri2.y);
        float e2  = __expf(-(dx2*dx2 + dy2*dy2 + dz2*dz2) * 0.5f * is2) + 2e-7f;
        if (!act2) e2 = 0.0f;
        float g2x = dx2*is2, g2y = dy2*is2, g2z = dz2*is2;
        float nu2 = e2 * ri2.x;

        float v[8] = { e1 + e2,
                       nu1 + nu2,
                       nu1*g1x + nu2*g2x,
                       nu1*g1y + nu2*g2y,
                       nu1*g1z + nu2*g2z,
                       e1*g1x + e2*g2x,
                       e1*g1y + e2*g2y,
                       e1*g1z + e2*g2z };
        red8_16(v);
        float ni  = v[0], nuA = v[1];
        float sx  = v[2], sy  = v[3], sz  = v[4];
        float sdx = v[5], sdy = v[6], sdz = v[7];

        float r   = __builtin_amdgcn_rcpf(ni);
        float rn  = ni * __builtin_amdgcn_rcpf(nuA);   // 1/n = norm/nu_s
        float in2 = r * r;
        float gx_ = (ni*sx - nuA*sdx) * in2;
        float gy_ = (ni*sy - nuA*sdy) * in2;
        float gz_ = (ni*sz - nuA*sdz) * in2;

        float dndx = gy_*M.drv[1] + gx_*M.drv[5] + gz_*M.drv[9]  + M.drv[13];
        float dndy = gy_*M.drv[0] + gx_*M.drv[4] + gz_*M.drv[8]  + M.drv[12];
        float dndz = gy_*M.drv[2] + gx_*M.drv[6] + gz_*M.drv[10] + M.drv[14];

        float dX2 = (dndx - dndz*dX) * (1.0f + dX*dX) * rn;
        float dY2 = (dndy - dndz*dY) * (1.0f + dY*dY) * rn;

        X = nX; Y = nY; z = nz;
        dX += dX2 * STEP;
        dY += dY2 * STEP;

        if (nb == 0) meshXT[s*NRAY2 + ray] = X*2.0f - 1.0f;
        if (nb == 1) meshYT[s*NRAY2 + ray] = Y*2.0f - 1.0f;

        cx_ = ncx; cy_ = ncy; cz_ = ncz;
        Xn1 = mX1; Yn1 = mY1; Zn1 = mZ1;
        Xn2 = mX2; Yn2 = mY2; Zn2 = mZ2;
        ri1 = ri1n; ri2 = ri2n;
    }
}

// ---------------- kernel 2: fused resize + grid sample ----------------------
typedef _Float16 h16;
typedef _Float16 h16v4 __attribute__((ext_vector_type(4)));

__global__ __launch_bounds__(1024) void sample_kernel(
    const float* __restrict__ vol,      // 192^3
    const float* __restrict__ meshXT,   // (64, 4096)
    const float* __restrict__ meshYT,
    h16*   __restrict__ outTh,          // fp16 transposed out [c][a*192+b]
    float* __restrict__ outDirect,      // fallback fp32 out [a][b][c]
    int transposed)
{
    __shared__ h16    plane_h[PLANE];     // 73,728 B
    __shared__ float2 slice[64*64];       // 32,768 B
    __shared__ float  wTab[PHD];
    __shared__ int    iTab[PHD];

    const int tid = threadIdx.x;
    const int blk = blockIdx.x;
    const int c = (blk >> 3) + 24 * (blk & 7);   // consecutive c on same XCD

    if (tid < PHD) {
        float p = tid * (63.0f / 191.0f);
        int i0 = min((int)p, 62);
        iTab[tid] = i0;
        wTab[tid] = p - (float)i0;
    }

    {
        const float4* src = (const float4*)(vol + c * PLANE);
        h16v4* dst = (h16v4*)plane_h;
        #pragma unroll
        for (int k = 0; k < (PLANE/4)/1024; ++k) {
            float4 v = src[tid + k*1024];
            h16v4 hv = {(h16)v.x, (h16)v.y, (h16)v.z, (h16)v.w};
            dst[tid + k*1024] = hv;
        }
    }

    float ps = c * (63.0f / 191.0f);
    int s0 = min((int)ps, 62);
    float wc = ps - (float)s0, wc0 = 1.0f - wc;
    {
        const float* x0 = meshXT + s0*NRAY2;
        const float* x1 = meshXT + (s0+1)*NRAY2;
        const float* y0 = meshYT + s0*NRAY2;
        const float* y1 = meshYT + (s0+1)*NRAY2;
        #pragma unroll
        for (int k = 0; k < 4096/1024; ++k) {
            int t = tid + k*1024;
            slice[t] = make_float2(x0[t]*wc0 + x1[t]*wc,
                                   y0[t]*wc0 + y1[t]*wc);
        }
    }
    __syncthreads();

    int a = tid / PHD, b = tid % PHD;
    #pragma unroll 4
    for (int k = 0; k < PLANE/1024; ++k) {
        int i0 = iTab[a]; float wa = wTab[a];
        int j0 = iTab[b]; float wb = wTab[b];

        float2 s00 = slice[i0*64 + j0];
        float2 s01 = slice[i0*64 + j0 + 1];
        float2 s10 = slice[(i0+1)*64 + j0];
        float2 s11 = slice[(i0+1)*64 + j0 + 1];

        float wb0 = 1.0f - wb, wa0 = 1.0f - wa;
        float gx = (s00.x*wb0 + s01.x*wb)*wa0 + (s10.x*wb0 + s11.x*wb)*wa;
        float gy = (s00.y*wb0 + s01.y*wb)*wa0 + (s10.y*wb0 + s11.y*wb)*wa;

        float ix = (gx + 1.0f) * 0.5f * 191.0f;
        float iy = (gy + 1.0f) * 0.5f * 191.0f;
        float x0f = floorf(ix); float fx = ix - x0f;
        float y0f = floorf(iy); float fy = iy - y0f;

        float acc = 0.0f;
        #pragma unroll
        for (int dyy = 0; dyy < 2; ++dyy) {
            #pragma unroll
            for (int dxx = 0; dxx < 2; ++dxx) {
                float xi = x0f + (float)dxx;
                float yi = y0f + (float)dyy;
                bool inb = (xi >= 0.0f) && (xi <= 191.0f) &&
                           (yi >= 0.0f) && (yi <= 191.0f);
                int xc = min(max((int)xi, 0), PHD - 1);
                int yc = min(max((int)yi, 0), PHD - 1);
                float w = (dxx ? fx : 1.0f - fx) * (dyy ? fy : 1.0f - fy);
                float val = (float)plane_h[yc*PHD + xc];
                acc += inb ? w * val : 0.0f;
            }
        }

        if (transposed) {
            outTh[c*PLANE + tid + k*1024] = (h16)acc;   // contiguous
        } else {
            outDirect[(a*PHD + b)*PHD + c] = acc;
        }

        a += 5; b += 64;
        if (b >= PHD) { b -= PHD; a += 1; }
    }
}

// ---------------- kernel 3: (b,c) tile transpose, fp16 -> fp32 --------------
__global__ __launch_bounds__(256) void transpose_kernel(
    const h16* __restrict__ outTh, float* __restrict__ out)
{
    __shared__ h16 t[64][66];
    const int a  = blockIdx.z;
    const int b0 = blockIdx.x * 64;
    const int c0 = blockIdx.y * 64;
    const int tx = threadIdx.x & 63;
    const int ty = threadIdx.x >> 6;     // 0..3

    const h16* src = outTh + (size_t)(c0 + ty) * PLANE + a*PHD + b0 + tx;
    #pragma unroll
    for (int j = 0; j < 16; ++j)
        t[ty + 4*j][tx] = src[(size_t)(4*j) * PLANE];
    __syncthreads();

    float* dst = out + (size_t)a * PLANE + (size_t)(b0 + ty) * PHD + c0 + tx;
    #pragma unroll
    for (int j = 0; j < 16; ++j)
        dst[(size_t)(4*j) * PHD] = (float)t[tx][ty + 4*j];
}

// ---------------- launch -----------------------------------------------------
extern "C" void kernel_launch(void* const* d_in, const int* in_sizes, int n_in,
                              void* d_out, int out_size, void* d_ws, size_t ws_size,
                              hipStream_t stream)
{
    const float* Phantom = (const float*)d_in[0];   // 192^3
    const float* RI      = (const float*)d_in[1];   // (64^3, 2)
    const float* RayInit = (const float*)d_in[2];   // (4096, 5)
    float* out = (float*)d_out;

    float* meshXT = (float*)d_ws;                   // (64, 4096)   1 MB
    float* meshYT = meshXT + NRAY2 * NSAMP;         // (64, 4096)   1 MB
    h16*   outTh  = (h16*)(meshYT + NRAY2 * NSAMP); // 192^3 fp16   14.2 MB

    const size_t need = (size_t)(2 * NRAY2 * NSAMP) * sizeof(float)
                      + (size_t)PHD * PLANE * sizeof(h16);
    const int use_transpose = (ws_size >= need) ? 1 : 0;

    Mats M;
    build_mats(M);

    ray_trace_kernel<<<NRAY2/16, 256, 0, stream>>>(RI, RayInit, meshXT, meshYT, M);

    if (use_transpose) {
        sample_kernel<<<PHD, 1024, 0, stream>>>(Phantom, meshXT, meshYT,
                                                outTh, nullptr, 1);
        transpose_kernel<<<dim3(3, 3, PHD), 256, 0, stream>>>(outTh, out);
    } else {
        sample_kernel<<<PHD, 1024, 0, stream>>>(Phantom, meshXT, meshYT,
                                                nullptr, out, 0);
    }
}